// Round 18
// baseline (76.994 us; speedup 1.0000x reference)
//
#include <hip/hip_runtime.h>

#define BB 8
#define CC 256
#define HH 96
#define WW 96
#define HWW (HH*WW)
#define NLOC 256        // local prototypes (MFMA path)
#define PPAD 257        // + global prototype
#define THRESH 0.95f
#define NORM_EPS 1e-4f

typedef __attribute__((ext_vector_type(8))) _Float16 f16x8;
typedef __attribute__((ext_vector_type(16))) float f32x16;

union H16 { _Float16 f; unsigned short u; };

// ---- fused kernel 0+1: mask pooling (8 blocks) + feature pooling (2048) ----
__global__ void k01(const float* __restrict__ sup_fts,
                    const float* __restrict__ sup_mask,
                    const float* __restrict__ true_bg,
                    float* __restrict__ protos,
                    float* __restrict__ validf,
                    float* __restrict__ masksum) {
    __shared__ float red[256];
    int blk = blockIdx.x;
    int t = threadIdx.x;
    if (blk < BB * CC) {
        int b = blk >> 8, c = blk & 255;
        int gy = t >> 4, gx = t & 15;
        const float* fb = sup_fts + ((size_t)b * CC + c) * HWW;
        const float* mb = sup_mask + (size_t)b * HWW;
        int base = gy * 6 * WW + gx * 6;
        float fs = 0.f, fm = 0.f;
        for (int r = 0; r < 6; ++r) {
            const float* rowf = fb + base + r * WW;
            const float* rowm = mb + base + r * WW;
#pragma unroll
            for (int h = 0; h < 3; ++h) {
                float2 v  = *(const float2*)(rowf + 2 * h);
                float2 mk = *(const float2*)(rowm + 2 * h);
                fs += v.x + v.y;
                fm = fmaf(v.x, mk.x, fm);
                fm = fmaf(v.y, mk.y, fm);
            }
        }
        protos[((size_t)b * PPAD + t) * CC + c] = fs * (1.f / 36.f);
        red[t] = fm;
        __syncthreads();
        for (int off = 128; off > 0; off >>= 1) {
            if (t < off) red[t] += red[t + off];
            __syncthreads();
        }
        if (t == 0) protos[((size_t)b * PPAD + 256) * CC + c] = red[0];
    } else {
        int b = blk - BB * CC;
        int gy = t >> 4, gx = t & 15;
        const float* mb = sup_mask + (size_t)b * HWW;
        const float* gb = true_bg  + (size_t)b * HWW;
        int base = gy * 6 * WW + gx * 6;
        float ms = 0.f, bs = 0.f;
        for (int r = 0; r < 6; ++r) {
            const float* rowm = mb + base + r * WW;
            const float* rowg = gb + base + r * WW;
#pragma unroll
            for (int h = 0; h < 3; ++h) {
                float2 mk = *(const float2*)(rowm + 2 * h);
                float2 bg2 = *(const float2*)(rowg + 2 * h);
                ms += mk.x + mk.y;
                bs += bg2.x + bg2.y;
            }
        }
        float mmean = ms * (1.f / 36.f);
        float bmean = bs * (1.f / 36.f);
        validf[b * PPAD + t] = (mmean > THRESH && bmean < 0.5f) ? 1.f : 0.f;
        if (t == 0) validf[b * PPAD + 256] = 1.f;
        red[t] = ms;
        __syncthreads();
        for (int off = 128; off > 0; off >>= 1) {
            if (t < off) red[t] += red[t + off];
            __syncthreads();
        }
        if (t == 0) masksum[b] = red[0];
    }
}

// ------- kernel 2: finish gproto + normalize + emit fp16 proto image --------
// Pimg layout (fp16): [B][16 kstep][2 khalf][8 tile][32 col][8 e]
__global__ void k2_norm(float* __restrict__ protos,
                        const float* __restrict__ masksum,
                        unsigned short* __restrict__ Pimg) {
    int bp = blockIdx.x;
    int b = bp / PPAD;
    int p = bp - b * PPAD;
    int t = threadIdx.x;            // channel
    float v = protos[((size_t)b * PPAD + p) * CC + t];
    if (p == 256) v = v / (masksum[b] + 1e-5f);
    __shared__ float red[256];
    red[t] = v * v;
    __syncthreads();
    for (int off = 128; off > 0; off >>= 1) {
        if (t < off) red[t] += red[t + off];
        __syncthreads();
    }
    float norm = sqrtf(red[0]);
    float vn = v / fmaxf(norm, NORM_EPS);
    protos[((size_t)b * PPAD + p) * CC + t] = vn;
    if (p < NLOC) {
        H16 h; h.f = (_Float16)vn;            // RNE, err 2^-11
        int kstep = t >> 4, khalf = (t >> 3) & 1, e = t & 7;
        int tile = p >> 5, col = p & 31;
        size_t idx = ((((size_t)b * 16 + kstep) * 2 + khalf) * 8 + tile) * 256
                     + col * 8 + e;
        Pimg[idx] = h.u;
    }
}

// ------- kernel 2q: DEDICATED q transpose+convert -> MFMA-ready image -------
// Reads q channel-major (coalesced 256B/instr, 64 independent loads/thread).
// Emits Qimg [B][288 tile][64 kq][32 px][4 ch] fp16. Write-out PAIRED:
// 8 x 16B stores/thread (r17 did 16 x 8B — half the store instructions).
__global__ __launch_bounds__(256, 4)
void k2q(const float* __restrict__ qry,
         const float* __restrict__ protos_n,
         unsigned short* __restrict__ Qimg,
         float* __restrict__ rns,
         float* __restrict__ gds) {
    __shared__ alignas(16) unsigned short T[64 * 64 * 4];   // [kq][px64][4] = 32 KB
    __shared__ float gpl[256];
    __shared__ float rn4[4][64], rg4[4][64];

    int blk = blockIdx.x;
    int b = blk / 144;
    int tp = blk - b * 144;          // tile-pair 0..143
    int px0 = tp * 64;
    int t = threadIdx.x;
    int px = t & 63;
    int cq = t >> 6;                 // channel quarter (64 ch)

    const float* gp = protos_n + ((size_t)b * PPAD + 256) * CC;
    gpl[t] = gp[t];
    __syncthreads();

    const float* qb = qry + (size_t)b * CC * HWW + px0 + px;
    float nrm = 0.f, gac = 0.f;
#pragma unroll
    for (int j = 0; j < 16; ++j) {   // 4 channels per j
        int c0 = cq * 64 + j * 4;
        unsigned int hh[4];
#pragma unroll
        for (int i = 0; i < 4; ++i) {
            float v = qb[(size_t)(c0 + i) * HWW];
            H16 x; x.f = (_Float16)v;          // RNE
            hh[i] = x.u;
            nrm = fmaf(v, v, nrm);
            gac = fmaf(v, gpl[c0 + i], gac);
        }
        uint2 pk;
        pk.x = hh[0] | (hh[1] << 16); pk.y = hh[2] | (hh[3] << 16);
        int kq = cq * 16 + j;
        *(uint2*)&T[(kq * 64 + px) * 4] = pk;  // px*8B -> 2-way max (free)
    }
    rn4[cq][px] = nrm;
    rg4[cq][px] = gac;
    __syncthreads();
    if (t < 64) {
        float n2 = rn4[0][t] + rn4[1][t] + rn4[2][t] + rn4[3][t];
        float gs = rg4[0][t] + rg4[1][t] + rg4[2][t] + rg4[3][t];
        float rn = 1.f / fmaxf(sqrtf(n2), NORM_EPS);
        rns[(size_t)b * HWW + px0 + t] = rn;
        gds[(size_t)b * HWW + px0 + t] = gs * rn;
    }

    // write out both 16KB tiles: [tile][kq][px32][4], px-paired 16B stores.
    // F-space: kq(64) x tile(2) x pl2(16) = 2048 = 8 x 256 threads.
    unsigned short* Qo = Qimg + ((size_t)b * 288 + (size_t)tp * 2) * 8192;
#pragma unroll
    for (int r = 0; r < 8; ++r) {
        int F = r * 256 + t;
        int pl2 = F & 15, tile = (F >> 4) & 1, kq = F >> 5;
        int pxx = tile * 32 + 2 * pl2;
        uint2 v0 = *(const uint2*)&T[(kq * 64 + pxx) * 4];
        uint2 v1 = *(const uint2*)&T[(kq * 64 + pxx + 1) * 4];
        uint4 pk; pk.x = v0.x; pk.y = v0.y; pk.z = v1.x; pk.w = v1.y;
        *(uint4*)&Qo[(size_t)tile * 8192 + (kq * 32 + 2 * pl2) * 4] = pk;
    }
}

// ---------------- kernel 3: MFMA dists + masked softmax + weighted sum ------
// NO LDS staging, NO pre-marathon barrier: A-fragments read DIRECTLY from
// Qimg global (lane-consecutive 8B = coalesced; L2/L3-resident), B from Pimg.
// Both streams 4-deep register lookahead; equal ~250-450cyc latency so
// in-order vmcnt entanglement is harmless. Marathon + r13-verified epilogue.
__global__ __launch_bounds__(256, 4)
void k3_mfma(const unsigned short* __restrict__ Qimg,
             const unsigned short* __restrict__ Pimg,
             const float* __restrict__ rns,
             const float* __restrict__ gds,
             const float* __restrict__ validf,
             float* __restrict__ out) {
    __shared__ float rn_s[32], gd_s[32];
    __shared__ float S_l[4][32], N_l[4][32];

    int blk = blockIdx.x;
    int b = blk & 7;                  // batch <-> XCD affinity
    int tile = blk >> 3;              // 0..287
    int px0 = tile * 32;
    int t = threadIdx.x;              // 0..255
    int l = t & 63;
    int w = t >> 6;                   // wave 0..3
    int col = l & 31;
    int h = l >> 5;

    const unsigned short* Qt = Qimg + ((size_t)b * 288 + tile) * 8192;
    const unsigned short* Pb = Pimg + (size_t)b * 65536;

    if (t < 32) {
        rn_s[t] = rns[(size_t)b * HWW + px0 + t];
        gd_s[t] = gds[(size_t)b * HWW + px0 + t];
    }

    f32x16 acc[2];
#pragma unroll
    for (int i = 0; i < 16; ++i) { acc[0][i] = 0.f; acc[1][i] = 0.f; }
    f16x8 Bf[4][2];
    uint2 qa[4][2];                   // Q-fragment stream, 4-deep

#define LOADQ(KS, BUF) {                                                      \
        int kq0 = (KS) * 4 + h * 2;                                           \
        qa[BUF][0] = *(const uint2*)&Qt[(kq0 * 32 + col) * 4];                \
        qa[BUF][1] = *(const uint2*)&Qt[((kq0 + 1) * 32 + col) * 4]; }

#define LOADB(KS, BUF) { _Pragma("unroll")                                    \
        for (int tix = 0; tix < 2; ++tix)                                     \
            Bf[BUF][tix] = *(const f16x8*)(Pb +                               \
                ((((size_t)(KS) * 2 + h) * 8 + (w * 2 + tix)) * 32 + col) * 8); }

    LOADQ(0, 0); LOADB(0, 0);
    LOADQ(1, 1); LOADB(1, 1);
    LOADQ(2, 2); LOADB(2, 2);
    LOADQ(3, 3); LOADB(3, 3);

    // ---- marathon: 16 ks x {2 MFMA}, Q+B 4-deep register streams ----
#pragma unroll
    for (int ks = 0; ks < 16; ++ks) {
        union { f16x8 v; unsigned int u[4]; } QA;
        QA.u[0] = qa[ks & 3][0].x; QA.u[1] = qa[ks & 3][0].y;
        QA.u[2] = qa[ks & 3][1].x; QA.u[3] = qa[ks & 3][1].y;
#pragma unroll
        for (int tix = 0; tix < 2; ++tix)
            acc[tix] = __builtin_amdgcn_mfma_f32_32x32x16_f16(QA.v, Bf[ks & 3][tix], acc[tix], 0, 0, 0);
        if (ks + 4 < 16) { LOADQ(ks + 4, ks & 3); LOADB(ks + 4, ks & 3); }
    }
#undef LOADQ
#undef LOADB

    __syncthreads();                  // rn_s/gd_s visible to all waves

    // ---- softmax epilogue (r13-verified) ----
    // D-map (m74/m101): proto = w*64 + tix*32 + col; row(px) = (r&3)+8*(r>>2)+4*h.
    float vf0 = validf[b * PPAD + w * 64 + col];
    float vf1 = validf[b * PPAD + w * 64 + 32 + col];
#pragma unroll
    for (int r = 0; r < 16; ++r) {
        int row = (r & 3) + 8 * (r >> 2) + 4 * h;
        float rnv = rn_s[row];
        float d0 = acc[0][r] * rnv;
        float d1 = acc[1][r] * rnv;
        float l0 = (vf0 != 0.f) ? d0 : -1e30f;
        float l1 = (vf1 != 0.f) ? d1 : -1e30f;
        float e0 = __expf(l0 - 1.1f);             // masked -> exactly 0
        float e1 = __expf(l1 - 1.1f);
        float s = e0 + e1;
        float nn = fmaf(e0, l0, e1 * l1);
#pragma unroll
        for (int m = 1; m < 32; m <<= 1) {        // reduce over 32 proto-cols
            s  += __shfl_xor(s, m);
            nn += __shfl_xor(nn, m);
        }
        if (col == 0) { S_l[w][row] = s; N_l[w][row] = nn; }
    }
    __syncthreads();

    if (t < 32) {
        float gdv = gd_s[t];
        float eg = __expf(gdv - 1.1f);            // global proto, exactly once
        float S = eg, N = eg * gdv;
#pragma unroll
        for (int i = 0; i < 4; ++i) { S += S_l[i][t]; N += N_l[i][t]; }
        out[(size_t)b * HWW + px0 + t] = N / S;
    }
}

extern "C" void kernel_launch(void* const* d_in, const int* in_sizes, int n_in,
                              void* d_out, int out_size, void* d_ws, size_t ws_size,
                              hipStream_t stream) {
    const float* qry = (const float*)d_in[0];
    const float* sup = (const float*)d_in[1];
    const float* msk = (const float*)d_in[2];
    const float* bg  = (const float*)d_in[3];
    float* out = (float*)d_out;

    float* ws = (float*)d_ws;
    float* protos  = ws;                                    // [B][257][256] f32
    float* validf  = protos + (size_t)BB * PPAD * CC;       // [B][257]
    float* masksum = validf + (size_t)BB * PPAD;            // [B]
    float* rns     = masksum + BB;                          // [B][9216]
    float* gds     = rns + (size_t)BB * HWW;                // [B][9216]
    unsigned short* Pimg = (unsigned short*)(gds + (size_t)BB * HWW); // 1 MB
    unsigned short* Qimg = Pimg + (size_t)BB * 65536;       // [B][288][8192] 37.75 MB

    hipLaunchKernelGGL(k01, dim3(BB * CC + BB), dim3(256), 0, stream,
                       sup, msk, bg, protos, validf, masksum);
    hipLaunchKernelGGL(k2_norm, dim3(BB * PPAD), dim3(256), 0, stream, protos, masksum, Pimg);
    hipLaunchKernelGGL(k2q, dim3(BB * 144), dim3(256), 0, stream,
                       qry, protos, Qimg, rns, gds);
    hipLaunchKernelGGL(k3_mfma, dim3(BB * (HWW / 32)), dim3(256), 0, stream,
                       Qimg, Pimg, rns, gds, validf, out);
}

// Round 19
// 58.078 us; speedup vs baseline: 1.3257x; 1.3257x over previous
//
#include <hip/hip_runtime.h>

#define BB 8
#define CC 256
#define HH 96
#define WW 96
#define HWW (HH*WW)
#define NLOC 256        // local prototypes (MFMA path)
#define PPAD 257        // + global prototype
#define THRESH 0.95f
#define NORM_EPS 1e-4f

typedef __attribute__((ext_vector_type(8))) _Float16 f16x8;
typedef __attribute__((ext_vector_type(16))) float f32x16;

union H16 { _Float16 f; unsigned short u; };

// ---- fused kernel 0+1: mask pooling (8 blocks) + feature pooling (2048) ----
__global__ void k01(const float* __restrict__ sup_fts,
                    const float* __restrict__ sup_mask,
                    const float* __restrict__ true_bg,
                    float* __restrict__ protos,
                    float* __restrict__ validf,
                    float* __restrict__ masksum) {
    __shared__ float red[256];
    int blk = blockIdx.x;
    int t = threadIdx.x;
    if (blk < BB * CC) {
        int b = blk >> 8, c = blk & 255;
        int gy = t >> 4, gx = t & 15;
        const float* fb = sup_fts + ((size_t)b * CC + c) * HWW;
        const float* mb = sup_mask + (size_t)b * HWW;
        int base = gy * 6 * WW + gx * 6;
        float fs = 0.f, fm = 0.f;
        for (int r = 0; r < 6; ++r) {
            const float* rowf = fb + base + r * WW;
            const float* rowm = mb + base + r * WW;
#pragma unroll
            for (int h = 0; h < 3; ++h) {
                float2 v  = *(const float2*)(rowf + 2 * h);
                float2 mk = *(const float2*)(rowm + 2 * h);
                fs += v.x + v.y;
                fm = fmaf(v.x, mk.x, fm);
                fm = fmaf(v.y, mk.y, fm);
            }
        }
        protos[((size_t)b * PPAD + t) * CC + c] = fs * (1.f / 36.f);
        red[t] = fm;
        __syncthreads();
        for (int off = 128; off > 0; off >>= 1) {
            if (t < off) red[t] += red[t + off];
            __syncthreads();
        }
        if (t == 0) protos[((size_t)b * PPAD + 256) * CC + c] = red[0];
    } else {
        int b = blk - BB * CC;
        int gy = t >> 4, gx = t & 15;
        const float* mb = sup_mask + (size_t)b * HWW;
        const float* gb = true_bg  + (size_t)b * HWW;
        int base = gy * 6 * WW + gx * 6;
        float ms = 0.f, bs = 0.f;
        for (int r = 0; r < 6; ++r) {
            const float* rowm = mb + base + r * WW;
            const float* rowg = gb + base + r * WW;
#pragma unroll
            for (int h = 0; h < 3; ++h) {
                float2 mk = *(const float2*)(rowm + 2 * h);
                float2 bg2 = *(const float2*)(rowg + 2 * h);
                ms += mk.x + mk.y;
                bs += bg2.x + bg2.y;
            }
        }
        float mmean = ms * (1.f / 36.f);
        float bmean = bs * (1.f / 36.f);
        validf[b * PPAD + t] = (mmean > THRESH && bmean < 0.5f) ? 1.f : 0.f;
        if (t == 0) validf[b * PPAD + 256] = 1.f;
        red[t] = ms;
        __syncthreads();
        for (int off = 128; off > 0; off >>= 1) {
            if (t < off) red[t] += red[t + off];
            __syncthreads();
        }
        if (t == 0) masksum[b] = red[0];
    }
}

// ------- kernel 2: finish gproto + normalize + emit fp16 proto image --------
// Pimg layout (fp16): [B][16 kstep][2 khalf][8 tile][32 col][8 e]
__global__ void k2_norm(float* __restrict__ protos,
                        const float* __restrict__ masksum,
                        unsigned short* __restrict__ Pimg) {
    int bp = blockIdx.x;
    int b = bp / PPAD;
    int p = bp - b * PPAD;
    int t = threadIdx.x;            // channel
    float v = protos[((size_t)b * PPAD + p) * CC + t];
    if (p == 256) v = v / (masksum[b] + 1e-5f);
    __shared__ float red[256];
    red[t] = v * v;
    __syncthreads();
    for (int off = 128; off > 0; off >>= 1) {
        if (t < off) red[t] += red[t + off];
        __syncthreads();
    }
    float norm = sqrtf(red[0]);
    float vn = v / fmaxf(norm, NORM_EPS);
    protos[((size_t)b * PPAD + p) * CC + t] = vn;
    if (p < NLOC) {
        H16 h; h.f = (_Float16)vn;            // RNE, err 2^-11
        int kstep = t >> 4, khalf = (t >> 3) & 1, e = t & 7;
        int tile = p >> 5, col = p & 31;
        size_t idx = ((((size_t)b * 16 + kstep) * 2 + khalf) * 8 + tile) * 256
                     + col * 8 + e;
        Pimg[idx] = h.u;
    }
}

// ---------------- kernel 3: MFMA dists + masked softmax + weighted sum ------
// r13 structure (best known: k3=50us) with TWO latency-targeted changes:
//  (a) __launch_bounds__(256, 8): LDS 19.7KB fits 8 blocks/CU (r13's bound
//      of 6 artificially capped occupancy at 55%). VGPR must stay <=64.
//  (b) BATCHED staging: issue all 32 q-loads into registers FIRST (ONE
//      latency exposure), then convert — r13 did 8 dependent load-convert
//      groups = ~4.8k serial cycles per block at VGPR=36.
// Marathon + epilogue byte-identical to r13 (verified D-map, conflicts=0).
__global__ __launch_bounds__(256, 8)
void k3_mfma(const float* __restrict__ qry,
             const unsigned short* __restrict__ Pimg,
             const float* __restrict__ protos_n,
             const float* __restrict__ validf,
             float* __restrict__ out) {
    __shared__ alignas(16) unsigned short Qf[64 * 128];    // [kq][px32][4 f16] = 16 KB
    __shared__ float red_n[8][32], red_g[8][32];
    __shared__ float rn_s[32], gd_s[32];
    __shared__ float S_l[4][32], N_l[4][32];

    int blk = blockIdx.x;
    int b = blk & 7;                  // batch <-> XCD affinity
    int tpx = blk >> 3;               // 0..287
    int px0 = tpx * 32;
    int t = threadIdx.x;              // 0..255
    int l = t & 63;
    int w = t >> 6;                   // wave 0..3
    int col = l & 31;                 // proto-col within tile / px for staging
    int h = l >> 5;                   // k-half lane bit

    int spx = t & 31;                 // staging: pixel
    int cg  = t >> 5;                 // staging: channel group (32 ch each)

    const float* qb = qry + (size_t)b * CC * HWW + px0 + spx;
    const float* gp = protos_n + ((size_t)b * PPAD + 256) * CC;
    const unsigned short* Pb = Pimg + (size_t)b * 65536;

    // hoisted epilogue operands (latency overlapped with staging)
    float vf0 = validf[b * PPAD + w * 64 + col];
    float vf1 = validf[b * PPAD + w * 64 + 32 + col];

    // ---- batched staging: ALL 32 q loads in flight, then convert ----
    float qv[32];
#pragma unroll
    for (int j = 0; j < 8; ++j) {
        int c0 = cg * 32 + j * 4;
#pragma unroll
        for (int i = 0; i < 4; ++i) qv[j * 4 + i] = qb[(size_t)(c0 + i) * HWW];
    }
    float nrm = 0.f, gac = 0.f;
#pragma unroll
    for (int j = 0; j < 8; ++j) {
        int c0 = cg * 32 + j * 4;
        unsigned int hh[4];
#pragma unroll
        for (int i = 0; i < 4; ++i) {
            float v = qv[j * 4 + i];
            H16 x; x.f = (_Float16)v;             // RNE
            hh[i] = x.u;
            nrm = fmaf(v, v, nrm);
            gac = fmaf(v, gp[c0 + i], gac);       // cg-uniform, L1-hot
        }
        int kq = cg * 8 + j;
        uint2 pk;
        pk.x = hh[0] | (hh[1] << 16); pk.y = hh[2] | (hh[3] << 16);
        *(uint2*)&Qf[kq * 128 + spx * 4] = pk;    // px*8B -> 2-way max (free)
    }
    red_n[cg][spx] = nrm;
    red_g[cg][spx] = gac;
    __syncthreads();                  // the ONLY pre-loop barrier
    if (t < 32) {
        float n2 = 0.f, gs = 0.f;
#pragma unroll
        for (int i = 0; i < 8; ++i) { n2 += red_n[i][t]; gs += red_g[i][t]; }
        float rn = 1.f / fmaxf(sqrtf(n2), NORM_EPS);
        rn_s[t] = rn;
        gd_s[t] = gs * rn;
    }

    // ---- accumulators + B stream (loop's only VMEM; L2-resident 128KB/b) --
    f32x16 acc[2];
#pragma unroll
    for (int i = 0; i < 16; ++i) { acc[0][i] = 0.f; acc[1][i] = 0.f; }
    f16x8 Bf[2][2];                   // [buf][tile]

#define LOADB(KS, BUF)                                                        \
    {                                                                         \
        _Pragma("unroll")                                                     \
        for (int ti = 0; ti < 2; ++ti)                                        \
            Bf[BUF][ti] = *(const f16x8*)(Pb +                                \
                ((((size_t)(KS) * 2 + h) * 8 + (w * 2 + ti)) * 32 + col) * 8);\
    }

    LOADB(0, 0);
    LOADB(1, 1);

    // ---- barrier-free marathon: 16 K-steps x {1 A-read, 2 MFMA} ----
#pragma unroll
    for (int ks = 0; ks < 16; ++ks) {
        int kq0 = ks * 4 + h * 2;
        uint2 a0 = *(const uint2*)&Qf[kq0 * 128 + col * 4];
        uint2 a1 = *(const uint2*)&Qf[(kq0 + 1) * 128 + col * 4];
        union { f16x8 v; unsigned int u[4]; } QA;
        QA.u[0] = a0.x; QA.u[1] = a0.y; QA.u[2] = a1.x; QA.u[3] = a1.y;
#pragma unroll
        for (int ti = 0; ti < 2; ++ti)
            acc[ti] = __builtin_amdgcn_mfma_f32_32x32x16_f16(QA.v, Bf[ks & 1][ti], acc[ti], 0, 0, 0);
        if (ks + 2 < 16) LOADB(ks + 2, ks & 1);
    }
#undef LOADB

    __syncthreads();                  // rn_s/gd_s visible

    // ---- softmax epilogue (r13-verified) ----
    // D-map (m74/m101): proto = w*64 + ti*32 + col (col = lane&31);
    // row(px) = (r&3) + 8*(r>>2) + 4*h.
#pragma unroll
    for (int r = 0; r < 16; ++r) {
        int row = (r & 3) + 8 * (r >> 2) + 4 * h;
        float rnv = rn_s[row];
        float d0 = acc[0][r] * rnv;
        float d1 = acc[1][r] * rnv;
        float l0 = (vf0 != 0.f) ? d0 : -1e30f;
        float l1 = (vf1 != 0.f) ? d1 : -1e30f;
        float e0 = __expf(l0 - 1.1f);             // masked -> exactly 0
        float e1 = __expf(l1 - 1.1f);
        float s = e0 + e1;
        float nn = fmaf(e0, l0, e1 * l1);
#pragma unroll
        for (int m = 1; m < 32; m <<= 1) {        // reduce over 32 proto-cols
            s  += __shfl_xor(s, m);
            nn += __shfl_xor(nn, m);
        }
        if (col == 0) { S_l[w][row] = s; N_l[w][row] = nn; }
    }
    __syncthreads();

    // ---- final merge: 4 wave-partials + global proto (once), store ----
    if (t < 32) {
        float gdv = gd_s[t];
        float eg = __expf(gdv - 1.1f);
        float S = eg, N = eg * gdv;
#pragma unroll
        for (int i = 0; i < 4; ++i) { S += S_l[i][t]; N += N_l[i][t]; }
        out[(size_t)b * HWW + px0 + t] = N / S;
    }
}

extern "C" void kernel_launch(void* const* d_in, const int* in_sizes, int n_in,
                              void* d_out, int out_size, void* d_ws, size_t ws_size,
                              hipStream_t stream) {
    const float* qry = (const float*)d_in[0];
    const float* sup = (const float*)d_in[1];
    const float* msk = (const float*)d_in[2];
    const float* bg  = (const float*)d_in[3];
    float* out = (float*)d_out;

    float* ws = (float*)d_ws;
    float* protos  = ws;                                   // [B][257][256] f32
    float* validf  = protos + (size_t)BB * PPAD * CC;      // [B][257]
    float* masksum = validf + (size_t)BB * PPAD;           // [B]
    unsigned short* Pimg = (unsigned short*)(masksum + BB); // [B][16][2][8][32][8] fp16

    hipLaunchKernelGGL(k01, dim3(BB * CC + BB), dim3(256), 0, stream,
                       sup, msk, bg, protos, validf, masksum);
    hipLaunchKernelGGL(k2_norm, dim3(BB * PPAD), dim3(256), 0, stream, protos, masksum, Pimg);
    hipLaunchKernelGGL(k3_mfma, dim3(BB * (HWW / 32)), dim3(256), 0, stream,
                       qry, Pimg, protos, validf, out);
}